// Round 1
// baseline (1065.268 us; speedup 1.0000x reference)
//
#include <hip/hip_runtime.h>

#define BB 128
#define TT 1024
#define HH 512
#define KK 50

__device__ __forceinline__ float rl_f(float x, int lane) {
    return __int_as_float(__builtin_amdgcn_readlane(__float_as_int(x), lane));
}

// ---------------------------------------------------------------------------
// Kernel 1: feats[bt][k] = sum_h hidden[bt][h] * W[k][h] + b[k]
// 128-row x 64-k tile (k padded 50->64), fp32 FMA, LDS-staged, transposed tiles
// so compute reads are b128.
// ---------------------------------------------------------------------------
__global__ __launch_bounds__(256, 4) void gemm_feats(
    const float* __restrict__ hidden, const float* __restrict__ W,
    const float* __restrict__ bias, float* __restrict__ feats)
{
    __shared__ float At[32][132];   // [h][row], padded to dodge bank conflicts
    __shared__ float Wt[32][68];    // [h][k],  k padded to 64 (+4 pad)
    const int tid = threadIdx.x;
    const int ri  = tid & 31;       // row group: rows ri*4..ri*4+3
    const int ki  = tid >> 5;       // k group:   k   ki*8..ki*8+7
    const long row0 = (long)blockIdx.x * 128;

    float acc[4][8];
    #pragma unroll
    for (int r = 0; r < 4; ++r)
        #pragma unroll
        for (int k = 0; k < 8; ++k) acc[r][k] = 0.f;

    for (int h0 = 0; h0 < HH; h0 += 32) {
        // stage A tile (128 rows x 32 h), coalesced float4, transposed into LDS
        #pragma unroll
        for (int it = 0; it < 4; ++it) {
            int idx = tid + 256 * it;
            int r = idx >> 3, hq = idx & 7;
            float4 a = *(const float4*)(hidden + (row0 + r) * HH + h0 + hq * 4);
            At[hq*4+0][r] = a.x; At[hq*4+1][r] = a.y;
            At[hq*4+2][r] = a.z; At[hq*4+3][r] = a.w;
        }
        // stage W tile (64 k x 32 h), zero-pad k>=50
        #pragma unroll
        for (int it = 0; it < 2; ++it) {
            int idx = tid + 256 * it;
            int k = idx >> 3, hq = idx & 7;
            float4 w = make_float4(0.f, 0.f, 0.f, 0.f);
            if (k < KK) w = *(const float4*)(W + k * HH + h0 + hq * 4);
            Wt[hq*4+0][k] = w.x; Wt[hq*4+1][k] = w.y;
            Wt[hq*4+2][k] = w.z; Wt[hq*4+3][k] = w.w;
        }
        __syncthreads();
        #pragma unroll
        for (int h = 0; h < 32; ++h) {
            float a[4], w[8];
            *(float4*)a     = *(const float4*)&At[h][ri * 4];
            *(float4*)w     = *(const float4*)&Wt[h][ki * 8];
            *(float4*)(w+4) = *(const float4*)&Wt[h][ki * 8 + 4];
            #pragma unroll
            for (int r = 0; r < 4; ++r)
                #pragma unroll
                for (int k = 0; k < 8; ++k)
                    acc[r][k] += a[r] * w[k];
        }
        __syncthreads();
    }
    #pragma unroll
    for (int r = 0; r < 4; ++r) {
        long row = row0 + ri * 4 + r;
        #pragma unroll
        for (int k = 0; k < 8; ++k) {
            int kg = ki * 8 + k;
            if (kg < KK) feats[row * KK + kg] = acc[r][k] + bias[kg];
        }
    }
}

// ---------------------------------------------------------------------------
// Kernel 2: Viterbi forward DP. One wave per batch. Lane j owns tag j.
// v broadcast via readlane; (val,idx) max-tree with strict-> so ties pick the
// FIRST index (numpy argmax semantics). bp stored as u8 [T-1][B][K].
// ---------------------------------------------------------------------------
__global__ __launch_bounds__(64, 1) void viterbi_fwd(
    const float* __restrict__ feats, const float* __restrict__ trans,
    const float* __restrict__ startT, const float* __restrict__ stopT,
    float* __restrict__ out_score, int* __restrict__ lastTag,
    unsigned char* __restrict__ bp)
{
    const int b  = blockIdx.x;
    const int j  = threadIdx.x;
    const int jc = j < KK ? j : KK - 1;   // clamp idle lanes, avoid OOB

    float tcol[KK];                        // trans[i][jc] for all i
    #pragma unroll
    for (int i = 0; i < KK; ++i) tcol[i] = trans[i * KK + jc];

    const float* fptr = feats + (size_t)b * TT * KK;
    float v = fptr[jc] + startT[jc];
    float fnext = fptr[KK + jc];

    #pragma unroll 1
    for (int t = 1; t < TT; ++t) {
        float f = fnext;
        if (t < TT - 1) fnext = fptr[(size_t)(t + 1) * KK + jc];

        float val[KK]; int idx[KK];
        #pragma unroll
        for (int i = 0; i < KK; ++i) { val[i] = rl_f(v, i) + tcol[i]; idx[i] = i; }

        // pairwise tree, sizes 50->25->13->7->4->2->1; index order preserved,
        // strict > keeps earlier index on ties
        const int NS[6] = {50, 25, 13, 7, 4, 2};
        #pragma unroll
        for (int s = 0; s < 6; ++s) {
            const int n = NS[s];
            #pragma unroll
            for (int i = 0; i < n / 2; ++i) {
                bool g = val[2*i+1] > val[2*i];
                val[i] = g ? val[2*i+1] : val[2*i];
                idx[i] = g ? idx[2*i+1] : idx[2*i];
            }
            if (n & 1) { val[n/2] = val[n-1]; idx[n/2] = idx[n-1]; }
        }

        if (j < KK)
            bp[((size_t)(t - 1) * BB + b) * KK + j] = (unsigned char)idx[0];
        v = f + val[0];
    }

    v += stopT[jc];
    // final argmax over tags (first-index on ties), uniform scalar scan
    float bestv = rl_f(v, 0); int besti = 0;
    #pragma unroll
    for (int i = 1; i < KK; ++i) {
        float x = rl_f(v, i);
        if (x > bestv) { bestv = x; besti = i; }
    }
    if (j == 0) { out_score[b] = bestv; lastTag[b] = besti; }
}

// ---------------------------------------------------------------------------
// Kernel 3a: chunk maps. Chunk c covers transitions k in [32c, min(32c+31,1022)].
// Lane j walks its chunk backward from every possible entry tag.
// ---------------------------------------------------------------------------
__global__ void bt_maps(const unsigned char* __restrict__ bp, int* __restrict__ M)
{
    const int b = blockIdx.x, c = blockIdx.y;
    const int j = threadIdx.x;
    if (j >= KK) return;
    const int lo = c * 32;
    const int hi = min(c * 32 + 31, TT - 2);
    int cur = j;
    for (int k = hi; k >= lo; --k)
        cur = bp[((size_t)k * BB + b) * KK + cur];
    M[(b * 32 + c) * KK + j] = cur;
}

// ---------------------------------------------------------------------------
// Kernel 3b: compose boundary tags serially (32 LDS steps), then 32 lanes
// re-walk their chunks emitting tags (as float32).
// ---------------------------------------------------------------------------
__global__ void bt_emit(const unsigned char* __restrict__ bp,
                        const int* __restrict__ M,
                        const int* __restrict__ lastTag,
                        float* __restrict__ tags)
{
    __shared__ int Ml[32][KK];
    __shared__ int e[33];
    const int b = blockIdx.x, tid = threadIdx.x;

    for (int i = tid; i < 32 * KK; i += 64)
        Ml[i / KK][i % KK] = M[b * 32 * KK + i];
    __syncthreads();

    if (tid == 0) {
        int cur = lastTag[b];
        e[32] = cur;
        for (int c = 31; c >= 0; --c) { cur = Ml[c][cur]; e[c] = cur; }
    }
    __syncthreads();

    if (tid < 32) {
        const int c  = tid;
        const int lo = c * 32;
        const int hi = min(c * 32 + 31, TT - 2);
        int cur = e[c + 1];                 // tag at time hi+1
        for (int k = hi; k >= lo; --k) {
            cur = bp[((size_t)k * BB + b) * KK + cur];
            tags[(size_t)b * TT + k] = (float)cur;
        }
    }
    if (tid == 32) tags[(size_t)b * TT + (TT - 1)] = (float)lastTag[b];
}

// ---------------------------------------------------------------------------
extern "C" void kernel_launch(void* const* d_in, const int* in_sizes, int n_in,
                              void* d_out, int out_size, void* d_ws, size_t ws_size,
                              hipStream_t stream)
{
    const float* hidden = (const float*)d_in[0];
    const float* W      = (const float*)d_in[1];
    const float* bias   = (const float*)d_in[2];
    const float* trans  = (const float*)d_in[3];
    const float* startT = (const float*)d_in[4];
    const float* stopT  = (const float*)d_in[5];

    float* out = (float*)d_out;           // [0:128] best_score, [128:] tags

    char* ws = (char*)d_ws;
    float*         feats = (float*)ws;                               // 26,214,400 B
    unsigned char* bp    = (unsigned char*)(ws + 26214400);          //  6,547,200 B
    int*           M     = (int*)(ws + 32761600);                    //    819,200 B
    int*           lastT = (int*)(ws + 33580800);                    //        512 B

    gemm_feats<<<dim3((BB * TT) / 128), 256, 0, stream>>>(hidden, W, bias, feats);
    viterbi_fwd<<<dim3(BB), 64, 0, stream>>>(feats, trans, startT, stopT,
                                             out, lastT, bp);
    bt_maps<<<dim3(BB, 32), 64, 0, stream>>>(bp, M);
    bt_emit<<<dim3(BB), 64, 0, stream>>>(bp, M, lastT, out + BB);
}

// Round 2
// 1062.201 us; speedup vs baseline: 1.0029x; 1.0029x over previous
//
#include <hip/hip_runtime.h>

#define BB 128
#define TT 1024
#define HH 512
#define KK 50

__device__ __forceinline__ float rl_f(float x, int lane) {
    return __int_as_float(__builtin_amdgcn_readlane(__float_as_int(x), lane));
}

// ---------------------------------------------------------------------------
// Kernel 1: feats[bt][k] = sum_h hidden[bt][h] * W[k][h] + b[k]
// 128-row x 64-k tile (k padded 50->64), fp32 FMA, LDS-staged, transposed tiles
// so compute reads are b128.  (unchanged this round — waiting for counters)
// ---------------------------------------------------------------------------
__global__ __launch_bounds__(256, 4) void gemm_feats(
    const float* __restrict__ hidden, const float* __restrict__ W,
    const float* __restrict__ bias, float* __restrict__ feats)
{
    __shared__ float At[32][132];   // [h][row], padded to dodge bank conflicts
    __shared__ float Wt[32][68];    // [h][k],  k padded to 64 (+4 pad)
    const int tid = threadIdx.x;
    const int ri  = tid & 31;       // row group: rows ri*4..ri*4+3
    const int ki  = tid >> 5;       // k group:   k   ki*8..ki*8+7
    const long row0 = (long)blockIdx.x * 128;

    float acc[4][8];
    #pragma unroll
    for (int r = 0; r < 4; ++r)
        #pragma unroll
        for (int k = 0; k < 8; ++k) acc[r][k] = 0.f;

    for (int h0 = 0; h0 < HH; h0 += 32) {
        #pragma unroll
        for (int it = 0; it < 4; ++it) {
            int idx = tid + 256 * it;
            int r = idx >> 3, hq = idx & 7;
            float4 a = *(const float4*)(hidden + (row0 + r) * HH + h0 + hq * 4);
            At[hq*4+0][r] = a.x; At[hq*4+1][r] = a.y;
            At[hq*4+2][r] = a.z; At[hq*4+3][r] = a.w;
        }
        #pragma unroll
        for (int it = 0; it < 2; ++it) {
            int idx = tid + 256 * it;
            int k = idx >> 3, hq = idx & 7;
            float4 w = make_float4(0.f, 0.f, 0.f, 0.f);
            if (k < KK) w = *(const float4*)(W + k * HH + h0 + hq * 4);
            Wt[hq*4+0][k] = w.x; Wt[hq*4+1][k] = w.y;
            Wt[hq*4+2][k] = w.z; Wt[hq*4+3][k] = w.w;
        }
        __syncthreads();
        #pragma unroll
        for (int h = 0; h < 32; ++h) {
            float a[4], w[8];
            *(float4*)a     = *(const float4*)&At[h][ri * 4];
            *(float4*)w     = *(const float4*)&Wt[h][ki * 8];
            *(float4*)(w+4) = *(const float4*)&Wt[h][ki * 8 + 4];
            #pragma unroll
            for (int r = 0; r < 4; ++r)
                #pragma unroll
                for (int k = 0; k < 8; ++k)
                    acc[r][k] += a[r] * w[k];
        }
        __syncthreads();
    }
    #pragma unroll
    for (int r = 0; r < 4; ++r) {
        long row = row0 + ri * 4 + r;
        #pragma unroll
        for (int k = 0; k < 8; ++k) {
            int kg = ki * 8 + k;
            if (kg < KK) feats[row * KK + kg] = acc[r][k] + bias[kg];
        }
    }
}

// ---------------------------------------------------------------------------
// Kernel 2: Viterbi forward DP. One wave per batch, lane j owns tag j.
// REGISTER-CLEAN rewrite: no stage tables, every tree stage has literal
// bounds and explicit carries so SROA cannot fail (R1 had VGPR=44 => scratch).
// Strict-> keeps the FIRST index on ties (numpy argmax semantics).
// ---------------------------------------------------------------------------
__global__ __launch_bounds__(64, 1) void viterbi_fwd(
    const float* __restrict__ feats, const float* __restrict__ trans,
    const float* __restrict__ startT, const float* __restrict__ stopT,
    float* __restrict__ out_score, int* __restrict__ lastTag,
    unsigned char* __restrict__ bp)
{
    const int b  = blockIdx.x;
    const int j  = threadIdx.x;
    const int jc = j < KK ? j : KK - 1;

    float tc[KK];                    // trans[i][jc], register-resident
    #pragma unroll
    for (int i = 0; i < KK; ++i) tc[i] = trans[i * KK + jc];

    const float* fptr = feats + (size_t)b * TT * KK;
    float v  = fptr[jc] + startT[jc];
    float f1 = fptr[KK + jc];        // feat[t=1]
    float f2 = fptr[2 * KK + jc];    // feat[t=2]

    unsigned char* bpb = bp + (size_t)b * KK + j;   // + t*(BB*KK) per step

    #pragma unroll 1
    for (int t = 1; t < TT; ++t) {
        float f = f1;
        f1 = f2;
        if (t + 2 < TT) f2 = fptr[(size_t)(t + 2) * KK + jc];

        float x[KK]; int ix[KK];
        #pragma unroll
        for (int i = 0; i < KK; ++i) { x[i] = rl_f(v, i) + tc[i]; ix[i] = i; }

        // 50 -> 25
        #pragma unroll
        for (int i = 0; i < 25; ++i) {
            bool g = x[2*i+1] > x[2*i];
            x[i]  = g ? x[2*i+1]  : x[2*i];
            ix[i] = g ? ix[2*i+1] : ix[2*i];
        }
        // 25 -> 13 (12 pairs + carry)
        #pragma unroll
        for (int i = 0; i < 12; ++i) {
            bool g = x[2*i+1] > x[2*i];
            x[i]  = g ? x[2*i+1]  : x[2*i];
            ix[i] = g ? ix[2*i+1] : ix[2*i];
        }
        x[12] = x[24]; ix[12] = ix[24];
        // 13 -> 7 (6 pairs + carry)
        #pragma unroll
        for (int i = 0; i < 6; ++i) {
            bool g = x[2*i+1] > x[2*i];
            x[i]  = g ? x[2*i+1]  : x[2*i];
            ix[i] = g ? ix[2*i+1] : ix[2*i];
        }
        x[6] = x[12]; ix[6] = ix[12];
        // 7 -> 4 (3 pairs + carry)
        #pragma unroll
        for (int i = 0; i < 3; ++i) {
            bool g = x[2*i+1] > x[2*i];
            x[i]  = g ? x[2*i+1]  : x[2*i];
            ix[i] = g ? ix[2*i+1] : ix[2*i];
        }
        x[3] = x[6]; ix[3] = ix[6];
        // 4 -> 2
        {
            bool g0 = x[1] > x[0];
            float xv0 = g0 ? x[1] : x[0]; int xi0 = g0 ? ix[1] : ix[0];
            bool g1 = x[3] > x[2];
            float xv1 = g1 ? x[3] : x[2]; int xi1 = g1 ? ix[3] : ix[2];
            // 2 -> 1
            bool g = xv1 > xv0;
            float m = g ? xv1 : xv0; int mi = g ? xi1 : xi0;

            if (j < KK)
                bpb[(size_t)(t - 1) * (BB * KK)] = (unsigned char)mi;
            v = f + m;
        }
    }

    v += stopT[jc];
    float bestv = rl_f(v, 0); int besti = 0;
    #pragma unroll
    for (int i = 1; i < KK; ++i) {
        float xx = rl_f(v, i);
        if (xx > bestv) { bestv = xx; besti = i; }
    }
    if (j == 0) { out_score[b] = bestv; lastTag[b] = besti; }
}

// ---------------------------------------------------------------------------
// Kernel 3a: chunk maps. Chunk c covers bp steps k in [32c, min(32c+31,1022)].
// ---------------------------------------------------------------------------
__global__ void bt_maps(const unsigned char* __restrict__ bp, int* __restrict__ M)
{
    const int b = blockIdx.x, c = blockIdx.y;
    const int j = threadIdx.x;
    if (j >= KK) return;
    const int lo = c * 32;
    const int hi = min(c * 32 + 31, TT - 2);
    int cur = j;
    for (int k = hi; k >= lo; --k)
        cur = bp[((size_t)k * BB + b) * KK + cur];
    M[(b * 32 + c) * KK + j] = cur;
}

// ---------------------------------------------------------------------------
// Kernel 3b: compose boundary tags serially, then 32 lanes re-walk chunks.
// ---------------------------------------------------------------------------
__global__ void bt_emit(const unsigned char* __restrict__ bp,
                        const int* __restrict__ M,
                        const int* __restrict__ lastTag,
                        float* __restrict__ tags)
{
    __shared__ int Ml[32][KK];
    __shared__ int e[33];
    const int b = blockIdx.x, tid = threadIdx.x;

    for (int i = tid; i < 32 * KK; i += 64)
        Ml[i / KK][i % KK] = M[b * 32 * KK + i];
    __syncthreads();

    if (tid == 0) {
        int cur = lastTag[b];
        e[32] = cur;
        for (int c = 31; c >= 0; --c) { cur = Ml[c][cur]; e[c] = cur; }
    }
    __syncthreads();

    if (tid < 32) {
        const int c  = tid;
        const int lo = c * 32;
        const int hi = min(c * 32 + 31, TT - 2);
        int cur = e[c + 1];
        for (int k = hi; k >= lo; --k) {
            cur = bp[((size_t)k * BB + b) * KK + cur];
            tags[(size_t)b * TT + k] = (float)cur;
        }
    }
    if (tid == 32) tags[(size_t)b * TT + (TT - 1)] = (float)lastTag[b];
}

// ---------------------------------------------------------------------------
extern "C" void kernel_launch(void* const* d_in, const int* in_sizes, int n_in,
                              void* d_out, int out_size, void* d_ws, size_t ws_size,
                              hipStream_t stream)
{
    const float* hidden = (const float*)d_in[0];
    const float* W      = (const float*)d_in[1];
    const float* bias   = (const float*)d_in[2];
    const float* trans  = (const float*)d_in[3];
    const float* startT = (const float*)d_in[4];
    const float* stopT  = (const float*)d_in[5];

    float* out = (float*)d_out;           // [0:128] best_score, [128:] tags

    char* ws = (char*)d_ws;
    float*         feats = (float*)ws;                               // 26,214,400 B
    unsigned char* bp    = (unsigned char*)(ws + 26214400);          //  6,547,200 B
    int*           M     = (int*)(ws + 32761600);                    //    819,200 B
    int*           lastT = (int*)(ws + 33580800);                    //        512 B

    gemm_feats<<<dim3((BB * TT) / 128), 256, 0, stream>>>(hidden, W, bias, feats);
    viterbi_fwd<<<dim3(BB), 64, 0, stream>>>(feats, trans, startT, stopT,
                                             out, lastT, bp);
    bt_maps<<<dim3(BB, 32), 64, 0, stream>>>(bp, M);
    bt_emit<<<dim3(BB), 64, 0, stream>>>(bp, M, lastT, out + BB);
}

// Round 3
// 776.686 us; speedup vs baseline: 1.3716x; 1.3676x over previous
//
#include <hip/hip_runtime.h>

#define BB 128
#define TT 1024
#define HH 512
#define KK 50

__device__ __forceinline__ float rl_f(float x, int lane) {
    return __int_as_float(__builtin_amdgcn_readlane(__float_as_int(x), lane));
}

// ---------------------------------------------------------------------------
// Kernel 1: feats[bt][k] = sum_h hidden[bt][h] * W[k][h] + b[k]
// (unchanged this round — counters for it arrive next round)
// ---------------------------------------------------------------------------
__global__ __launch_bounds__(256, 4) void gemm_feats(
    const float* __restrict__ hidden, const float* __restrict__ W,
    const float* __restrict__ bias, float* __restrict__ feats)
{
    __shared__ float At[32][132];
    __shared__ float Wt[32][68];
    const int tid = threadIdx.x;
    const int ri  = tid & 31;
    const int ki  = tid >> 5;
    const long row0 = (long)blockIdx.x * 128;

    float acc[4][8];
    #pragma unroll
    for (int r = 0; r < 4; ++r)
        #pragma unroll
        for (int k = 0; k < 8; ++k) acc[r][k] = 0.f;

    for (int h0 = 0; h0 < HH; h0 += 32) {
        #pragma unroll
        for (int it = 0; it < 4; ++it) {
            int idx = tid + 256 * it;
            int r = idx >> 3, hq = idx & 7;
            float4 a = *(const float4*)(hidden + (row0 + r) * HH + h0 + hq * 4);
            At[hq*4+0][r] = a.x; At[hq*4+1][r] = a.y;
            At[hq*4+2][r] = a.z; At[hq*4+3][r] = a.w;
        }
        #pragma unroll
        for (int it = 0; it < 2; ++it) {
            int idx = tid + 256 * it;
            int k = idx >> 3, hq = idx & 7;
            float4 w = make_float4(0.f, 0.f, 0.f, 0.f);
            if (k < KK) w = *(const float4*)(W + k * HH + h0 + hq * 4);
            Wt[hq*4+0][k] = w.x; Wt[hq*4+1][k] = w.y;
            Wt[hq*4+2][k] = w.z; Wt[hq*4+3][k] = w.w;
        }
        __syncthreads();
        #pragma unroll
        for (int h = 0; h < 32; ++h) {
            float a[4], w[8];
            *(float4*)a     = *(const float4*)&At[h][ri * 4];
            *(float4*)w     = *(const float4*)&Wt[h][ki * 8];
            *(float4*)(w+4) = *(const float4*)&Wt[h][ki * 8 + 4];
            #pragma unroll
            for (int r = 0; r < 4; ++r)
                #pragma unroll
                for (int k = 0; k < 8; ++k)
                    acc[r][k] += a[r] * w[k];
        }
        __syncthreads();
    }
    #pragma unroll
    for (int r = 0; r < 4; ++r) {
        long row = row0 + ri * 4 + r;
        #pragma unroll
        for (int k = 0; k < 8; ++k) {
            int kg = ki * 8 + k;
            if (kg < KK) feats[row * KK + kg] = acc[r][k] + bias[kg];
        }
    }
}

// ---------------------------------------------------------------------------
// Kernel 2: bp-FREE Viterbi forward. One wave per batch, lane j owns tag j.
// Values-only max (no index tree, no bp write). v[t] overwrites feats[t]
// in place. Lanes 50..63 mirror lane 49 (identical values) so stores are
// unguarded (dup-address, dup-value — harmless).
// ---------------------------------------------------------------------------
__global__ __launch_bounds__(64, 1) void viterbi_fwd(
    float* __restrict__ fv, const float* __restrict__ trans,
    const float* __restrict__ startT, const float* __restrict__ stopT,
    float* __restrict__ out_score, int* __restrict__ lastTag)
{
    const int b  = blockIdx.x;
    const int j  = threadIdx.x;
    const int jc = j < KK ? j : KK - 1;

    float tc[KK];                    // trans[i][jc]; live set ~75 VGPR total
    #pragma unroll
    for (int i = 0; i < KK; ++i) tc[i] = trans[i * KK + jc];

    float* p = fv + (size_t)b * TT * KK;
    float v  = p[jc] + startT[jc];
    p[jc] = v;                        // v_0
    float f1 = p[KK + jc];
    float f2 = p[2 * KK + jc];

    #pragma unroll 1
    for (int t = 1; t < TT; ++t) {
        float f = f1; f1 = f2;
        if (t + 2 < TT) f2 = p[(size_t)(t + 2) * KK + jc];

        float x[KK];
        #pragma unroll
        for (int i = 0; i < KK; ++i) x[i] = rl_f(v, i) + tc[i];

        // values-only max tree: 50 -> 17 -> 6 -> 2 -> 1 (max3-shaped)
        float y[17];
        #pragma unroll
        for (int i = 0; i < 16; ++i)
            y[i] = fmaxf(fmaxf(x[3*i], x[3*i+1]), x[3*i+2]);
        y[16] = fmaxf(x[48], x[49]);
        float z[6];
        #pragma unroll
        for (int i = 0; i < 5; ++i)
            z[i] = fmaxf(fmaxf(y[3*i], y[3*i+1]), y[3*i+2]);
        z[5] = fmaxf(y[15], y[16]);
        float m = fmaxf(fmaxf(fmaxf(z[0], z[1]), z[2]),
                        fmaxf(fmaxf(z[3], z[4]), z[5]));

        v = f + m;
        p[(size_t)t * KK + jc] = v;   // store v_t over feats_t
    }

    v += stopT[jc];
    float bestv = rl_f(v, 0); int besti = 0;
    #pragma unroll
    for (int i = 1; i < KK; ++i) {
        float xx = rl_f(v, i);
        if (xx > bestv) { bestv = xx; besti = i; }
    }
    if (j == 0) { out_score[b] = bestv; lastTag[b] = besti; }
}

// ---------------------------------------------------------------------------
// Kernel 3a: RECOMPUTE backpointers in parallel chunks + chunk maps.
// Grid (b, c): wave walks bp-steps s in [32c, min(32c+31,1022)] downward.
// bp_s[j] = argmax_i(v_s[i] + T[i][j]), strict-> => first index on ties.
// 4096 waves => 4 waves/SIMD, latency hidden. Also materializes bp for emit.
// ---------------------------------------------------------------------------
__global__ __launch_bounds__(64, 4) void bt_maps(
    const float* __restrict__ v, const float* __restrict__ trans,
    unsigned char* __restrict__ bp, int* __restrict__ M)
{
    const int b = blockIdx.x, c = blockIdx.y;
    const int j = threadIdx.x;
    const int jc = j < KK ? j : KK - 1;

    float tc[KK];
    #pragma unroll
    for (int i = 0; i < KK; ++i) tc[i] = trans[i * KK + jc];

    const float* vb = v + (size_t)b * TT * KK;
    const int lo = c * 32;
    const int hi = min(c * 32 + 31, TT - 2);

    int cur = jc;
    float vnext = vb[(size_t)hi * KK + jc];

    #pragma unroll 1
    for (int s = hi; s >= lo; --s) {
        float vl = vnext;
        if (s > lo) vnext = vb[(size_t)(s - 1) * KK + jc];

        float x[KK]; int ix[KK];
        #pragma unroll
        for (int i = 0; i < KK; ++i) { x[i] = rl_f(vl, i) + tc[i]; ix[i] = i; }

        // pairwise first-index-tie argmax tree (50->25->13->7->4->2->1)
        #pragma unroll
        for (int i = 0; i < 25; ++i) {
            bool g = x[2*i+1] > x[2*i];
            x[i]  = g ? x[2*i+1]  : x[2*i];
            ix[i] = g ? ix[2*i+1] : ix[2*i];
        }
        #pragma unroll
        for (int i = 0; i < 12; ++i) {
            bool g = x[2*i+1] > x[2*i];
            x[i]  = g ? x[2*i+1]  : x[2*i];
            ix[i] = g ? ix[2*i+1] : ix[2*i];
        }
        x[12] = x[24]; ix[12] = ix[24];
        #pragma unroll
        for (int i = 0; i < 6; ++i) {
            bool g = x[2*i+1] > x[2*i];
            x[i]  = g ? x[2*i+1]  : x[2*i];
            ix[i] = g ? ix[2*i+1] : ix[2*i];
        }
        x[6] = x[12]; ix[6] = ix[12];
        #pragma unroll
        for (int i = 0; i < 3; ++i) {
            bool g = x[2*i+1] > x[2*i];
            x[i]  = g ? x[2*i+1]  : x[2*i];
            ix[i] = g ? ix[2*i+1] : ix[2*i];
        }
        x[3] = x[6]; ix[3] = ix[6];
        bool g0 = x[1] > x[0];
        float xv0 = g0 ? x[1] : x[0]; int xi0 = g0 ? ix[1] : ix[0];
        bool g1 = x[3] > x[2];
        float xv1 = g1 ? x[3] : x[2]; int xi1 = g1 ? ix[3] : ix[2];
        bool g = xv1 > xv0;
        int mi = g ? xi1 : xi0;

        if (j < KK)
            bp[((size_t)s * BB + b) * KK + j] = (unsigned char)mi;

        cur = __shfl(mi, cur, 64);    // compose: cur = bp_s[cur]
    }

    if (j < KK) M[(b * 32 + c) * KK + j] = cur;
}

// ---------------------------------------------------------------------------
// Kernel 3b: compose boundary tags serially, then 32 lanes re-walk chunks.
// ---------------------------------------------------------------------------
__global__ void bt_emit(const unsigned char* __restrict__ bp,
                        const int* __restrict__ M,
                        const int* __restrict__ lastTag,
                        float* __restrict__ tags)
{
    __shared__ int Ml[32][KK];
    __shared__ int e[33];
    const int b = blockIdx.x, tid = threadIdx.x;

    for (int i = tid; i < 32 * KK; i += 64)
        Ml[i / KK][i % KK] = M[b * 32 * KK + i];
    __syncthreads();

    if (tid == 0) {
        int cur = lastTag[b];
        e[32] = cur;
        for (int c = 31; c >= 0; --c) { cur = Ml[c][cur]; e[c] = cur; }
    }
    __syncthreads();

    if (tid < 32) {
        const int c  = tid;
        const int lo = c * 32;
        const int hi = min(c * 32 + 31, TT - 2);
        int cur = e[c + 1];
        for (int k = hi; k >= lo; --k) {
            cur = bp[((size_t)k * BB + b) * KK + cur];
            tags[(size_t)b * TT + k] = (float)cur;
        }
    }
    if (tid == 32) tags[(size_t)b * TT + (TT - 1)] = (float)lastTag[b];
}

// ---------------------------------------------------------------------------
extern "C" void kernel_launch(void* const* d_in, const int* in_sizes, int n_in,
                              void* d_out, int out_size, void* d_ws, size_t ws_size,
                              hipStream_t stream)
{
    const float* hidden = (const float*)d_in[0];
    const float* W      = (const float*)d_in[1];
    const float* bias   = (const float*)d_in[2];
    const float* trans  = (const float*)d_in[3];
    const float* startT = (const float*)d_in[4];
    const float* stopT  = (const float*)d_in[5];

    float* out = (float*)d_out;           // [0:128] best_score, [128:] tags

    char* ws = (char*)d_ws;
    float*         fv    = (float*)ws;                               // 26,214,400 B (feats -> v in place)
    unsigned char* bp    = (unsigned char*)(ws + 26214400);          //  6,547,200 B
    int*           M     = (int*)(ws + 32761600);                    //    819,200 B
    int*           lastT = (int*)(ws + 33580800);                    //        512 B

    gemm_feats<<<dim3((BB * TT) / 128), 256, 0, stream>>>(hidden, W, bias, fv);
    viterbi_fwd<<<dim3(BB), 64, 0, stream>>>(fv, trans, startT, stopT, out, lastT);
    bt_maps<<<dim3(BB, 32), 64, 0, stream>>>(fv, trans, bp, M);
    bt_emit<<<dim3(BB), 64, 0, stream>>>(bp, M, lastT, out + BB);
}

// Round 4
// 769.095 us; speedup vs baseline: 1.3851x; 1.0099x over previous
//
#include <hip/hip_runtime.h>

#define BB 128
#define TT 1024
#define HH 512
#define KK 50

__device__ __forceinline__ float rl_f(float x, int lane) {
    return __int_as_float(__builtin_amdgcn_readlane(__float_as_int(x), lane));
}

// Opaque register barrier: forces A[B..B+9] to be VGPR-resident at this point;
// loads feeding these cannot sink into the loop, results cannot be remat'd.
#define PIN10(A,B) asm volatile("" : "+v"(A[B+0]),"+v"(A[B+1]),"+v"(A[B+2]), \
    "+v"(A[B+3]),"+v"(A[B+4]),"+v"(A[B+5]),"+v"(A[B+6]),"+v"(A[B+7]), \
    "+v"(A[B+8]),"+v"(A[B+9]))
#define PIN50(A) do { PIN10(A,0); PIN10(A,10); PIN10(A,20); PIN10(A,30); PIN10(A,40); } while (0)

// ---------------------------------------------------------------------------
// Kernel 1: feats[bt][k] = sum_h hidden[bt][h] * W[k][h] + b[k]
// (unchanged — counters for it arrive next round once fwd shrinks)
// ---------------------------------------------------------------------------
__global__ __launch_bounds__(256, 4) void gemm_feats(
    const float* __restrict__ hidden, const float* __restrict__ W,
    const float* __restrict__ bias, float* __restrict__ feats)
{
    __shared__ float At[32][132];
    __shared__ float Wt[32][68];
    const int tid = threadIdx.x;
    const int ri  = tid & 31;
    const int ki  = tid >> 5;
    const long row0 = (long)blockIdx.x * 128;

    float acc[4][8];
    #pragma unroll
    for (int r = 0; r < 4; ++r)
        #pragma unroll
        for (int k = 0; k < 8; ++k) acc[r][k] = 0.f;

    for (int h0 = 0; h0 < HH; h0 += 32) {
        #pragma unroll
        for (int it = 0; it < 4; ++it) {
            int idx = tid + 256 * it;
            int r = idx >> 3, hq = idx & 7;
            float4 a = *(const float4*)(hidden + (row0 + r) * HH + h0 + hq * 4);
            At[hq*4+0][r] = a.x; At[hq*4+1][r] = a.y;
            At[hq*4+2][r] = a.z; At[hq*4+3][r] = a.w;
        }
        #pragma unroll
        for (int it = 0; it < 2; ++it) {
            int idx = tid + 256 * it;
            int k = idx >> 3, hq = idx & 7;
            float4 w = make_float4(0.f, 0.f, 0.f, 0.f);
            if (k < KK) w = *(const float4*)(W + k * HH + h0 + hq * 4);
            Wt[hq*4+0][k] = w.x; Wt[hq*4+1][k] = w.y;
            Wt[hq*4+2][k] = w.z; Wt[hq*4+3][k] = w.w;
        }
        __syncthreads();
        #pragma unroll
        for (int h = 0; h < 32; ++h) {
            float a[4], w[8];
            *(float4*)a     = *(const float4*)&At[h][ri * 4];
            *(float4*)w     = *(const float4*)&Wt[h][ki * 8];
            *(float4*)(w+4) = *(const float4*)&Wt[h][ki * 8 + 4];
            #pragma unroll
            for (int r = 0; r < 4; ++r)
                #pragma unroll
                for (int k = 0; k < 8; ++k)
                    acc[r][k] += a[r] * w[k];
        }
        __syncthreads();
    }
    #pragma unroll
    for (int r = 0; r < 4; ++r) {
        long row = row0 + ri * 4 + r;
        #pragma unroll
        for (int k = 0; k < 8; ++k) {
            int kg = ki * 8 + k;
            if (kg < KK) feats[row * KK + kg] = acc[r][k] + bias[kg];
        }
    }
}

// ---------------------------------------------------------------------------
// Kernel 2: bp-free Viterbi forward, tc PINNED in VGPRs.
// One wave per batch, lane j owns tag j; v[t] overwrites feats[t] in place.
// ---------------------------------------------------------------------------
__global__ __launch_bounds__(64, 1) void viterbi_fwd(
    float* __restrict__ fv, const float* __restrict__ trans,
    const float* __restrict__ startT, const float* __restrict__ stopT,
    float* __restrict__ out_score, int* __restrict__ lastTag)
{
    const int b  = blockIdx.x;
    const int j  = threadIdx.x;
    const int jc = j < KK ? j : KK - 1;

    float tc[KK];
    #pragma unroll
    for (int i = 0; i < KK; ++i) tc[i] = trans[i * KK + jc];
    PIN50(tc);                       // <- forces residency; kills in-loop reloads

    float* p = fv + (size_t)b * TT * KK;
    float v  = p[jc] + startT[jc];
    p[jc] = v;
    float f1 = p[KK + jc];
    float f2 = p[2 * KK + jc];
    float f3 = p[3 * KK + jc];

    #pragma unroll 1
    for (int t = 1; t < TT; ++t) {
        float f = f1; f1 = f2; f2 = f3;
        if (t + 3 < TT) f3 = p[(size_t)(t + 3) * KK + jc];

        float x[KK];
        #pragma unroll
        for (int i = 0; i < KK; ++i) x[i] = rl_f(v, i) + tc[i];

        float y[17];
        #pragma unroll
        for (int i = 0; i < 16; ++i)
            y[i] = fmaxf(fmaxf(x[3*i], x[3*i+1]), x[3*i+2]);
        y[16] = fmaxf(x[48], x[49]);
        float z[6];
        #pragma unroll
        for (int i = 0; i < 5; ++i)
            z[i] = fmaxf(fmaxf(y[3*i], y[3*i+1]), y[3*i+2]);
        z[5] = fmaxf(y[15], y[16]);
        float m = fmaxf(fmaxf(fmaxf(z[0], z[1]), z[2]),
                        fmaxf(fmaxf(z[3], z[4]), z[5]));

        v = f + m;
        p[(size_t)t * KK + jc] = v;
    }

    v += stopT[jc];
    float bestv = rl_f(v, 0); int besti = 0;
    #pragma unroll
    for (int i = 1; i < KK; ++i) {
        float xx = rl_f(v, i);
        if (xx > bestv) { bestv = xx; besti = i; }
    }
    if (j == 0) { out_score[b] = bestv; lastTag[b] = besti; }
}

// ---------------------------------------------------------------------------
// Kernel 3a: recompute backpointers per 32-step chunk + chunk maps.
// tc PINNED; sequential strict-> argmax scan (first index on ties, low
// register pressure -> fits 4 waves/EU).
// ---------------------------------------------------------------------------
__global__ __launch_bounds__(64, 4) void bt_maps(
    const float* __restrict__ v, const float* __restrict__ trans,
    unsigned char* __restrict__ bp, int* __restrict__ M)
{
    const int b = blockIdx.x, c = blockIdx.y;
    const int j = threadIdx.x;
    const int jc = j < KK ? j : KK - 1;

    float tc[KK];
    #pragma unroll
    for (int i = 0; i < KK; ++i) tc[i] = trans[i * KK + jc];
    PIN50(tc);

    const float* vb = v + (size_t)b * TT * KK;
    const int lo = c * 32;
    const int hi = min(c * 32 + 31, TT - 2);

    int cur = jc;
    float vnext = vb[(size_t)hi * KK + jc];

    #pragma unroll 1
    for (int s = hi; s >= lo; --s) {
        float vl = vnext;
        if (s > lo) vnext = vb[(size_t)(s - 1) * KK + jc];

        float best = rl_f(vl, 0) + tc[0];
        int   bi   = 0;
        #pragma unroll
        for (int i = 1; i < KK; ++i) {
            float cand = rl_f(vl, i) + tc[i];
            bool g = cand > best;            // strict: first index wins ties
            best = g ? cand : best;
            bi   = g ? i : bi;
        }

        if (j < KK)
            bp[((size_t)s * BB + b) * KK + j] = (unsigned char)bi;

        cur = __shfl(bi, cur, 64);           // compose: cur = bp_s[cur]
    }

    if (j < KK) M[(b * 32 + c) * KK + j] = cur;
}

// ---------------------------------------------------------------------------
// Kernel 3b: compose boundary tags serially, then 32 lanes re-walk chunks.
// ---------------------------------------------------------------------------
__global__ void bt_emit(const unsigned char* __restrict__ bp,
                        const int* __restrict__ M,
                        const int* __restrict__ lastTag,
                        float* __restrict__ tags)
{
    __shared__ int Ml[32][KK];
    __shared__ int e[33];
    const int b = blockIdx.x, tid = threadIdx.x;

    for (int i = tid; i < 32 * KK; i += 64)
        Ml[i / KK][i % KK] = M[b * 32 * KK + i];
    __syncthreads();

    if (tid == 0) {
        int cur = lastTag[b];
        e[32] = cur;
        for (int c = 31; c >= 0; --c) { cur = Ml[c][cur]; e[c] = cur; }
    }
    __syncthreads();

    if (tid < 32) {
        const int c  = tid;
        const int lo = c * 32;
        const int hi = min(c * 32 + 31, TT - 2);
        int cur = e[c + 1];
        for (int k = hi; k >= lo; --k) {
            cur = bp[((size_t)k * BB + b) * KK + cur];
            tags[(size_t)b * TT + k] = (float)cur;
        }
    }
    if (tid == 32) tags[(size_t)b * TT + (TT - 1)] = (float)lastTag[b];
}

// ---------------------------------------------------------------------------
extern "C" void kernel_launch(void* const* d_in, const int* in_sizes, int n_in,
                              void* d_out, int out_size, void* d_ws, size_t ws_size,
                              hipStream_t stream)
{
    const float* hidden = (const float*)d_in[0];
    const float* W      = (const float*)d_in[1];
    const float* bias   = (const float*)d_in[2];
    const float* trans  = (const float*)d_in[3];
    const float* startT = (const float*)d_in[4];
    const float* stopT  = (const float*)d_in[5];

    float* out = (float*)d_out;           // [0:128] best_score, [128:] tags

    char* ws = (char*)d_ws;
    float*         fv    = (float*)ws;                               // feats -> v in place
    unsigned char* bp    = (unsigned char*)(ws + 26214400);
    int*           M     = (int*)(ws + 32761600);
    int*           lastT = (int*)(ws + 33580800);

    gemm_feats<<<dim3((BB * TT) / 128), 256, 0, stream>>>(hidden, W, bias, fv);
    viterbi_fwd<<<dim3(BB), 64, 0, stream>>>(fv, trans, startT, stopT, out, lastT);
    bt_maps<<<dim3(BB, 32), 64, 0, stream>>>(fv, trans, bp, M);
    bt_emit<<<dim3(BB), 64, 0, stream>>>(bp, M, lastT, out + BB);
}